// Round 12
// baseline (404.227 us; speedup 1.0000x reference)
//
#include <hip/hip_runtime.h>
#include <hip/hip_bf16.h>

typedef _Float16 half8 __attribute__((ext_vector_type(8)));
typedef float f32x4 __attribute__((ext_vector_type(4)));

#define B_SZ 64
#define T_SZ 512
#define E_SZ 768
#define H_SZ 256
#define V_SZ 3072

// workspace layout (bytes)
#define WS_X     0u          // _Float16 x[T][B][H]           16,777,216 B
#define WS_WT    16777216u   // _Float16 Wt[256][768] (Wxh^T)    393,216 B
#define WS_WF    17170432u   // _Float16 Wf[65536] Whh MFMA-B    131,072 B
#define WS_H     17301504u   // float    h[64][256]               65,536 B

// fast tanh: 1 - 2/(1+exp(2x)); exact at +/-inf, ~1e-6 rel err
static __device__ __forceinline__ float fast_tanh(float x) {
  float e = __builtin_amdgcn_exp2f(x * 2.8853900817779268f); // exp(2x)
  return 1.0f - 2.0f * __builtin_amdgcn_rcpf(1.0f + e);
}

// ---------------- k0: prep f16 weight layouts (small) ----------------
// Wt[h][e] = Wxh[e][h] (k1 B panels).
// Wf = Whh in 16x16x32 MFMA-B fragment order (r7-validated):
//   frag(nt,kt)[lane][j] = Whh[kt*32 + (lane>>4)*8 + j][nt*16 + (lane&15)]
//   flat = ((nt*8+kt)*64+lane)*8 + j
__global__ __launch_bounds__(256) void k0_convert(
    const float* __restrict__ Wxh,
    const float* __restrict__ Whh,
    _Float16* __restrict__ Wt,
    _Float16* __restrict__ Wf)
{
  int gid = blockIdx.x * 256 + threadIdx.x;           // 768 WGs = 196608
  if (gid < E_SZ * H_SZ) {
    int e = gid >> 8, h = gid & 255;
    Wt[h * E_SZ + e] = (_Float16)Wxh[gid];
  }
  if (gid < 65536) {
    int j = gid & 7, lane = (gid >> 3) & 63, kt = (gid >> 9) & 7, nt = gid >> 12;
    int quad = lane >> 4, n16 = lane & 15;
    int row = kt * 32 + quad * 8 + j, col = nt * 16 + n16;
    Wf[gid] = (_Float16)Whh[row * H_SZ + col];
  }
}

// ---------------- k1: x[t,b,:] = emb[idx[b,t],:] @ Wxh  (MFMA f16) ----------------
// Double-buffered B panel: ONE barrier per ki.
__global__ __launch_bounds__(256) void k1_xproj(
    const int* __restrict__ idx,
    const float* __restrict__ emb,
    const _Float16* __restrict__ Wt,
    _Float16* __restrict__ x)
{
  const int tid  = threadIdx.x;
  const int w    = tid >> 6;
  const int lane = tid & 63;
  const int m16  = lane & 15;
  const int quad = lane >> 4;
  const int r = blockIdx.x * 64 + w * 16 + m16;     // row in [T*B], r = t*64 + b
  const int t = r >> 6;
  const int b = r & 63;
  const int erow = idx[b * T_SZ + t];
  const float* Arow = emb + (size_t)erow * E_SZ + quad * 8;   // A[m][k=quad*8+j]

  __shared__ __align__(16) _Float16 bp[2][16 * 64 * 8]; // 2 x 16KB fragment panels
  int n_[4], kb_[4];
#pragma unroll
  for (int pp = 0; pp < 4; ++pp) {
    int f = tid + 256 * pp;
    n_[pp]  = ((f >> 6) << 4) | (f & 15);
    kb_[pp] = (f >> 4) & 3;
  }
  uint4 stg[4];
#pragma unroll
  for (int pp = 0; pp < 4; ++pp)
    stg[pp] = *(const uint4*)(Wt + (size_t)n_[pp] * E_SZ + kb_[pp] * 8);
  f32x4 af0 = *(const f32x4*)(Arow);
  f32x4 af1 = *(const f32x4*)(Arow + 4);

  f32x4 acc[16];
#pragma unroll
  for (int n = 0; n < 16; ++n) { f32x4 z = {0.f, 0.f, 0.f, 0.f}; acc[n] = z; }

  // stage panel 0
#pragma unroll
  for (int pp = 0; pp < 4; ++pp)
    *(uint4*)(bp[0] + (size_t)(tid + 256 * pp) * 8) = stg[pp];
  __syncthreads();

#pragma unroll 1
  for (int ki = 0; ki < 24; ++ki) {
    const _Float16* cur = bp[ki & 1];
    f32x4 af0n = af0, af1n = af1;
    if (ki < 23) {                            // prefetch next panel + next A
#pragma unroll
      for (int pp = 0; pp < 4; ++pp)
        stg[pp] = *(const uint4*)(Wt + (size_t)n_[pp] * E_SZ + (ki + 1) * 32 + kb_[pp] * 8);
      af0n = *(const f32x4*)(Arow + (ki + 1) * 32);
      af1n = *(const f32x4*)(Arow + (ki + 1) * 32 + 4);
    }
    half8 a;
#pragma unroll
    for (int e = 0; e < 4; ++e) { a[e] = (_Float16)af0[e]; a[4 + e] = (_Float16)af1[e]; }
#pragma unroll
    for (int nt = 0; nt < 16; ++nt) {
      half8 bb = *(const half8*)(cur + (size_t)(nt * 64 + lane) * 8);
      acc[nt] = __builtin_amdgcn_mfma_f32_16x16x32_f16(a, bb, acc[nt], 0, 0, 0);
    }
    if (ki < 23) {                            // write next buffer, one barrier
#pragma unroll
      for (int pp = 0; pp < 4; ++pp)
        *(uint4*)(bp[(ki + 1) & 1] + (size_t)(tid + 256 * pp) * 8) = stg[pp];
      __syncthreads();
    }
    af0 = af0n; af1 = af1n;
  }
  const int rbase = blockIdx.x * 64 + w * 16 + quad * 4;  // C/D: col=lane&15, row=quad*4+reg
#pragma unroll
  for (int nt = 0; nt < 16; ++nt) {
    const int col = nt * 16 + m16;
#pragma unroll
    for (int rg = 0; rg < 4; ++rg) {
      x[(size_t)(rbase + rg) * H_SZ + col] = (_Float16)acc[nt][rg];
    }
  }
}

// ---------------- k2: MFMA recurrence w/ rotated K-order + same-wave pre-read
// Wave w owns N-tiles nt=w*4+c -> h-columns [64w,64w+64) = K-tiles 2w,2w+1.
// AGPR slot s of N-tile c holds B-frag for kt=(2w+s)&7 (wave-rotated park), so
// the static asm consumes the wave's OWN two K-tiles first. Those two A-frags
// are pre-read at the END of the previous step right after this wave's own
// ds_write (same-wave LDS ordering needs no barrier) — their ~120 cyc latency
// overlaps the barrier instead of stalling the first MFMA.
#define LDFRAG(C, S, R0, R1, R2, R3) { \
  uint4 q = Wf4[(((size_t)(w * 4 + C) * 8 + ((koff + S) & 7)) * 64) + lane]; \
  asm volatile("v_accvgpr_write_b32 a" #R0 ", %0" :: "v"(q.x) : "a" #R0); \
  asm volatile("v_accvgpr_write_b32 a" #R1 ", %0" :: "v"(q.y) : "a" #R1); \
  asm volatile("v_accvgpr_write_b32 a" #R2 ", %0" :: "v"(q.z) : "a" #R2); \
  asm volatile("v_accvgpr_write_b32 a" #R3 ", %0" :: "v"(q.w) : "a" #R3); }

// slot 0: fresh accumulators from pinned zero
#define MFMA_K0(A0, Z) \
  asm volatile( \
    "v_mfma_f32_16x16x32_f16 %[t0], %[a], a[0:3],   %[z]\n\t" \
    "v_mfma_f32_16x16x32_f16 %[t1], %[a], a[32:35], %[z]\n\t" \
    "v_mfma_f32_16x16x32_f16 %[t2], %[a], a[64:67], %[z]\n\t" \
    "v_mfma_f32_16x16x32_f16 %[t3], %[a], a[96:99], %[z]" \
    : [t0] "=&v"(acc0), [t1] "=&v"(acc1), [t2] "=&v"(acc2), [t3] "=&v"(acc3) \
    : [a] "v"(A0), [z] "v"(Z));

#define MFMA_KT(A0, B0, B1, B2, B3) \
  asm volatile( \
    "v_mfma_f32_16x16x32_f16 %[t0], %[a], a[" #B0 "], %[t0]\n\t" \
    "v_mfma_f32_16x16x32_f16 %[t1], %[a], a[" #B1 "], %[t1]\n\t" \
    "v_mfma_f32_16x16x32_f16 %[t2], %[a], a[" #B2 "], %[t2]\n\t" \
    "v_mfma_f32_16x16x32_f16 %[t3], %[a], a[" #B3 "], %[t3]" \
    : [t0] "+v"(acc0), [t1] "+v"(acc1), [t2] "+v"(acc2), [t3] "+v"(acc3) \
    : [a] "v"(A0));

#define MFMA_K7(A0, B0, B1, B2, B3) \
  asm volatile( \
    "v_mfma_f32_16x16x32_f16 %[t0], %[a], a[" #B0 "], %[t0]\n\t" \
    "v_mfma_f32_16x16x32_f16 %[t1], %[a], a[" #B1 "], %[t1]\n\t" \
    "v_mfma_f32_16x16x32_f16 %[t2], %[a], a[" #B2 "], %[t2]\n\t" \
    "v_mfma_f32_16x16x32_f16 %[t3], %[a], a[" #B3 "], %[t3]\n\t" \
    "s_nop 7\n\t" \
    "s_nop 7" \
    : [t0] "+v"(acc0), [t1] "+v"(acc1), [t2] "+v"(acc2), [t3] "+v"(acc3) \
    : [a] "v"(A0));

__global__ __launch_bounds__(256) void k2_rnn(
    const _Float16* __restrict__ Wf,
    const _Float16* __restrict__ x,
    const float* __restrict__ Bh,
    float* __restrict__ hout,
    float* __restrict__ hidout)
{
  const int b    = blockIdx.x;
  const int tid  = threadIdx.x;
  const int w    = tid >> 6;
  const int lane = tid & 63;
  const int quad = lane >> 4;
  const int q8   = quad * 8;
  const int koff = 2 * w;                          // wave's K-rotation
  __shared__ __align__(16) _Float16 hb[2][H_SZ];   // h as f16, double-buffered
  const uint4* Wf4 = (const uint4*)Wf;

  LDFRAG(0,0,  0,  1,  2,  3)  LDFRAG(0,1,  4,  5,  6,  7)
  LDFRAG(0,2,  8,  9, 10, 11)  LDFRAG(0,3, 12, 13, 14, 15)
  LDFRAG(0,4, 16, 17, 18, 19)  LDFRAG(0,5, 20, 21, 22, 23)
  LDFRAG(0,6, 24, 25, 26, 27)  LDFRAG(0,7, 28, 29, 30, 31)
  LDFRAG(1,0, 32, 33, 34, 35)  LDFRAG(1,1, 36, 37, 38, 39)
  LDFRAG(1,2, 40, 41, 42, 43)  LDFRAG(1,3, 44, 45, 46, 47)
  LDFRAG(1,4, 48, 49, 50, 51)  LDFRAG(1,5, 52, 53, 54, 55)
  LDFRAG(1,6, 56, 57, 58, 59)  LDFRAG(1,7, 60, 61, 62, 63)
  LDFRAG(2,0, 64, 65, 66, 67)  LDFRAG(2,1, 68, 69, 70, 71)
  LDFRAG(2,2, 72, 73, 74, 75)  LDFRAG(2,3, 76, 77, 78, 79)
  LDFRAG(2,4, 80, 81, 82, 83)  LDFRAG(2,5, 84, 85, 86, 87)
  LDFRAG(2,6, 88, 89, 90, 91)  LDFRAG(2,7, 92, 93, 94, 95)
  LDFRAG(3,0, 96, 97, 98, 99)  LDFRAG(3,1,100,101,102,103)
  LDFRAG(3,2,104,105,106,107)  LDFRAG(3,3,108,109,110,111)
  LDFRAG(3,4,112,113,114,115)  LDFRAG(3,5,116,117,118,119)
  LDFRAG(3,6,120,121,122,123)  LDFRAG(3,7,124,125,126,127)

  const float bhj = Bh[tid];
  const _Float16* xp = x + b * H_SZ + tid;
  _Float16 xq = xp[0];
  f32x4 zero4 = {0.f, 0.f, 0.f, 0.f};
  asm volatile("" : "+v"(zero4));        // pin: no remat-mov adjacent to MFMA srcC
  hb[1][tid] = (_Float16)0.f;            // t=0 reads buffer 1 = zeros
  float hval = 0.f;
  __syncthreads();
  // pre-read the wave's own two A-frags (slots 0,1) for t=0
  half8 va0 = *(const half8*)(hb[1] + ((((koff + 0) & 7) << 5) + q8));
  half8 va1 = *(const half8*)(hb[1] + ((((koff + 1) & 7) << 5) + q8));

#pragma unroll 1
  for (int t = 0; t < T_SZ; ++t) {
    const int tn = (t < T_SZ - 1) ? (t + 1) : t;
    _Float16 xn = xp[(size_t)tn * (B_SZ * H_SZ)];   // prefetch next x
    const _Float16* hr = hb[(t + 1) & 1];
    // remaining A-frags (other waves' columns): post-barrier reads
    half8 va2 = *(const half8*)(hr + ((((koff + 2) & 7) << 5) + q8));
    half8 va3 = *(const half8*)(hr + ((((koff + 3) & 7) << 5) + q8));
    half8 va4 = *(const half8*)(hr + ((((koff + 4) & 7) << 5) + q8));
    half8 va5 = *(const half8*)(hr + ((((koff + 5) & 7) << 5) + q8));
    half8 va6 = *(const half8*)(hr + ((((koff + 6) & 7) << 5) + q8));
    half8 va7 = *(const half8*)(hr + ((((koff + 7) & 7) << 5) + q8));
    f32x4 acc0, acc1, acc2, acc3;
    MFMA_K0(va0, zero4)
    MFMA_KT(va1,   4:7,  36:39,  68:71, 100:103)
    MFMA_KT(va2,  8:11,  40:43,  72:75, 104:107)
    MFMA_KT(va3, 12:15,  44:47,  76:79, 108:111)
    MFMA_KT(va4, 16:19,  48:51,  80:83, 112:115)
    MFMA_KT(va5, 20:23,  52:55,  84:87, 116:119)
    MFMA_KT(va6, 24:27,  56:59,  88:91, 120:123)
    MFMA_K7(va7, 28:31,  60:63,  92:95, 124:127)
    // D rows identical (A rows replicated); lane (quad q, n16) takes tile q:
    float v0 = acc0[0], v1 = acc1[0], v2 = acc2[0], v3 = acc3[0];
    float ylo = (quad & 1) ? v1 : v0;
    float yhi = (quad & 1) ? v3 : v2;
    float y   = (quad & 2) ? yhi : ylo;     // y = (h @ Whh)[tid]
    hval = fast_tanh(y + (float)xq + bhj);
    _Float16* hw = hb[t & 1];
    hw[tid] = (_Float16)hval;
    // pre-read own slots 0,1 for next step — same-wave write->read, no barrier
    va0 = *(const half8*)(hw + ((((koff + 0) & 7) << 5) + q8));
    va1 = *(const half8*)(hw + ((((koff + 1) & 7) << 5) + q8));
    __syncthreads();
    xq = xn;
  }
  hout[b * H_SZ + tid] = hval;
  hidout[b * H_SZ + tid] = hval;
}

// ---------------- k3: out = hidden @ Wy + By  (all f32) ----------------
__global__ __launch_bounds__(256) void k3_out(
    const float* __restrict__ h,
    const float* __restrict__ Wy,
    const float* __restrict__ By,
    float* __restrict__ out)
{
  __shared__ float hs[H_SZ];
  const int c = blockIdx.x;   // vocab chunk
  const int b = blockIdx.y;   // batch
  const int v = c * 256 + threadIdx.x;
  hs[threadIdx.x] = h[b * H_SZ + threadIdx.x];
  __syncthreads();
  float acc = By[v];
#pragma unroll 8
  for (int jj = 0; jj < H_SZ; ++jj) {
    acc += hs[jj] * Wy[(size_t)jj * V_SZ + v];
  }
  out[(size_t)b * V_SZ + v] = acc;
}

extern "C" void kernel_launch(void* const* d_in, const int* in_sizes, int n_in,
                              void* d_out, int out_size, void* d_ws, size_t ws_size,
                              hipStream_t stream)
{
  const int*   idx = (const int*)d_in[0];
  const float* emb = (const float*)d_in[1];
  const float* Wxh = (const float*)d_in[2];
  const float* Whh = (const float*)d_in[3];
  const float* Wy  = (const float*)d_in[4];
  const float* By  = (const float*)d_in[5];
  const float* Bh  = (const float*)d_in[6];

  char* ws = (char*)d_ws;
  _Float16* x    = (_Float16*)(ws + WS_X);
  _Float16* Wt   = (_Float16*)(ws + WS_WT);
  _Float16* Wf   = (_Float16*)(ws + WS_WF);
  float*    hbuf = (float*)(ws + WS_H);

  float* out    = (float*)d_out;
  float* hidout = out + (size_t)B_SZ * V_SZ;

  k0_convert<<<768, 256, 0, stream>>>(Wxh, Whh, Wt, Wf);
  k1_xproj  <<<512, 256, 0, stream>>>(idx, emb, Wt, x);
  k2_rnn    <<<64, 256, 0, stream>>>(Wf, x, Bh, hbuf, hidout);
  k3_out    <<<dim3(12, 64), 256, 0, stream>>>(hbuf, Wy, By, out);
}